// Round 7
// baseline (74.076 us; speedup 1.0000x reference)
//
#include <hip/hip_runtime.h>
#include <math.h>

#define BATCH 4096
#define DIM 256
#define FPC 8
#define NPAIR 14336   // 512 groups * C(8,2)
#define SHIFT 22.0f
#define NT 32         // 32 stripes of 128 rows
#define NTILE (NT * (NT + 1) / 2)   // 528 upper-triangular 128x128 tiles
#define DGRID 512     // dist grid = 2 blocks/CU co-residency; 16 blocks take a 2nd tile
#define S_Q (127.0f / 6.0f)          // int8 quant scale (|x|<6 for N(0,1))
#define K2 (2.0f * (6.0f / 127.0f) * (6.0f / 127.0f))   // d2 -= K2*idot
#define LOG2E 1.442695040888963f
#define NSHL2 (-(SHIFT * LOG2E))     // -22*log2(e): exp(d-22)=exp2(d*log2e+NSHL2)
#define PGRP 4                       // FPC-groups per pairs block / numerator block
#define PSLOT 64                     // P slots per row (2 per touching tile)

typedef int   i32x4 __attribute__((ext_vector_type(4)));

// async global->LDS, 16B per lane; dest = wave-uniform base + lane*16
__device__ __forceinline__ void g2l16(const void* g, void* l) {
    __builtin_amdgcn_global_load_lds((__attribute__((address_space(1))) void*)(g),
                                     (__attribute__((address_space(3))) void*)(l),
                                     16, 0, 0);
}

// ---------------------------------------------------------------------------
// ws layout (floats): [0,4096) sq ; [4096, 4096+4096*64) P partials ;
// then xq int8 (1 MB) ; then DD[512*28] fp32 pair distances.
// P[r][k]: 64 conflict-free partial exp-sums per row, written exactly once
// by construction (no zero-init, no atomics).
// R7: pair-distance numerators (depend only on x) hoisted into prep's extra
// blocks -> pairs kernel is just {P-reduce, 112 log/exp lanes, 1 atomic}.
// NOTE (R2/R3/R5 lessons): cross-block fusion via completion counters was
// 60-130us SLOWER (agent-RELEASE emits buffer_wbl2 = L2 flush storm; even
// relaxed sc1 paths idle at ~90us). R5: fire-and-forget fp32 atomicAdd into
// S[4096] cost +10us (TCC RMW serialization on shared lines). Plain L2
// store/load + kernel-boundary coherence wins. Do not re-fuse, no atomics.
// Harness floor per iteration: 268MB poison fill (~41us @82% HBM) + ~30 tiny
// reset dispatches -> ~55-60us not controllable from here.
// ---------------------------------------------------------------------------

__global__ __launch_bounds__(256) void prep_kernel(const float* __restrict__ x,
                                                   float* __restrict__ sq,
                                                   signed char* __restrict__ xq,
                                                   float* __restrict__ DD,
                                                   float* __restrict__ out) {
    const int tid = threadIdx.x;
    if (blockIdx.x < BATCH / 4) {
        // ---- quantize + row sumsq: blocks 0..1023, one wave per row ----
        int t = blockIdx.x * 256 + tid;
        int row = t >> 6;
        int lane = t & 63;
        float4 v = ((const float4*)(x + row * DIM))[lane];
        // int8 symmetric quantization, RNE
        int qx = (int)rintf(v.x * S_Q), qy = (int)rintf(v.y * S_Q);
        int qz = (int)rintf(v.z * S_Q), qw = (int)rintf(v.w * S_Q);
        qx = max(-127, min(127, qx)); qy = max(-127, min(127, qy));
        qz = max(-127, min(127, qz)); qw = max(-127, min(127, qw));
        unsigned pk = (unsigned)(qx & 255) | ((unsigned)(qy & 255) << 8) |
                      ((unsigned)(qz & 255) << 16) | ((unsigned)(qw & 255) << 24);
        ((unsigned*)(xq + (size_t)row * DIM))[lane] = pk;
        float s = v.x * v.x + v.y * v.y + v.z * v.z + v.w * v.w;
#pragma unroll
        for (int off = 32; off > 0; off >>= 1) s += __shfl_xor(s, off);
        if (lane == 0) sq[row] = s;
        if (t == 0) out[0] = 0.f;
    } else {
        // ---- pair-distance numerators: blocks 1024..1151 (x-only, runs
        // concurrently with quantize; instruction sequence identical to the
        // old pairs phase-2 -> bit-identical dd) ----
        const int pb = blockIdx.x - BATCH / 4;        // 0..127
        const int base0 = pb * (FPC * PGRP);
        const int p = tid >> 3;     // pair id 0..31 (28 used)
        const int g = tid & 7;      // lane within pair group
        int a = 0, b = 0;
        if (p < 28) {
            int q = p;
            while (q >= 7 - a) { q -= 7 - a; a++; }
            b = a + 1 + q;                          // anchor=a, positive=b
        }
#pragma unroll
        for (int it = 0; it < PGRP; it++) {
            if (p < 28) {
                const int base = base0 + it * FPC;
                const float4* xa  = (const float4*)(x + (size_t)(base + a) * DIM);
                const float4* xbp = (const float4*)(x + (size_t)(base + b) * DIM);
                float d2 = 0.f;
#pragma unroll
                for (int r = 0; r < 8; r++) {
                    float4 va = xa[r * 8 + g], vb = xbp[r * 8 + g];
                    float dx = va.x - vb.x, dy = va.y - vb.y;
                    float dz = va.z - vb.z, dw = va.w - vb.w;
                    d2 = fmaf(dx, dx, d2); d2 = fmaf(dy, dy, d2);
                    d2 = fmaf(dz, dz, d2); d2 = fmaf(dw, dw, d2);
                }
                d2 += __shfl_xor(d2, 1);
                d2 += __shfl_xor(d2, 2);
                d2 += __shfl_xor(d2, 4);
                if (g == 0) {
                    float dd = sqrtf(fmaxf(d2, 0.f));
                    DD[(size_t)(pb * PGRP + it) * 28 + p] = dd;
                }
            }
        }
    }
}

// 128x128 upper-triangular tile of dist = sqrt(sq_r - 2*s^2*idot + sq_c),
// i8 MFMA K=64, K=256 staged in TWO 128-wide phases -> 32KB LDS.
// 4 waves in 2x2; each wave owns a 64x64 quadrant (4x4 16x16 frags, 64 acc
// VGPRs, 64 MFMAs). Chunk-XOR swizzle (16B chunks, 8/row): global chunk g
// of row r -> slot g^(r&7); reader slot (kk*4+quad)^(lcol&7) -> 2-way bank
// aliasing (free). Row exp-sums -> P[row][2*bj+wc]; off-diag tiles also
// mirrored col exp-sums -> P[col][2*bi+wr]. Grid 512 (=2/CU capacity);
// stride loop folds tiles 512..527 into blocks 0..15 (no 16-block tail round).
__global__ __launch_bounds__(256, 2) void dist_kernel(const signed char* __restrict__ xq,
                                                      const float* __restrict__ sq,
                                                      float* __restrict__ P) {
    __shared__ signed char As[128][128];   // 16KB
    __shared__ signed char Bs[128][128];   // 16KB

    const int tid  = threadIdx.x;
    const int w    = tid >> 6;      // wave 0..3
    const int lane = tid & 63;
    const int wr   = w >> 1;        // wave row 0..1 (64-row half)
    const int wc   = w & 1;         // wave col 0..1
    const int quad = lane >> 4;     // 0..3
    const int lcol = lane & 15;     // 0..15

    // staging: one g2l16 = 8 rows x 128B; lane -> (row lane>>3, chunk lane&7)
    const int srow = lane >> 3;     // 0..7
    const int schk = lane & 7;      // linear LDS chunk (16B units)
    const int gc = (schk ^ (srow & 7)) * 16;   // swizzled global chunk (bytes)
    const int ldsoff = lane * 16;   // linear LDS dest (bytes)

    for (int tile = blockIdx.x; tile < NTILE; tile += DGRID) {
        // triangular decode: tile (bi, bj) with bi <= bj
        int t = tile, bi = 0;
        while (t >= NT - bi) { t -= NT - bi; bi++; }
        const int bj = bi + t;
        const int row0 = bi * 128;
        const int col0 = bj * 128;
        const bool diagblk = (bi == bj);

        i32x4 acc[4][4];
#pragma unroll
        for (int i = 0; i < 4; i++)
#pragma unroll
            for (int j = 0; j < 4; j++) {
                i32x4 z = {0, 0, 0, 0};
                acc[i][j] = z;
            }

#pragma unroll
        for (int ph = 0; ph < 2; ph++) {
            const int k0 = ph * 128;
            __syncthreads();        // prior phase's (or prior tile's) LDS reads done
#pragma unroll
            for (int c = 0; c < 4; c++) {
                const int rb = w * 32 + c * 8;   // wave w stages rows [w*32, w*32+32)
                const int r  = rb + srow;
                g2l16(xq + (size_t)(row0 + r) * DIM + k0 + gc, (signed char*)&As[rb][0] + ldsoff);
                g2l16(xq + (size_t)(col0 + r) * DIM + k0 + gc, (signed char*)&Bs[rb][0] + ldsoff);
            }
            __syncthreads();        // drain: 32KB staged

#pragma unroll
            for (int kk = 0; kk < 2; kk++) {
                const int slot = ((kk * 4 + quad) ^ (lcol & 7)) * 16;
                i32x4 a[4], bb[4];
#pragma unroll
                for (int i = 0; i < 4; i++)
                    a[i] = *(const i32x4*)&As[wr * 64 + i * 16 + lcol][slot];
#pragma unroll
                for (int j = 0; j < 4; j++)
                    bb[j] = *(const i32x4*)&Bs[wc * 64 + j * 16 + lcol][slot];
#pragma unroll
                for (int i = 0; i < 4; i++)
#pragma unroll
                    for (int j = 0; j < 4; j++)
                        acc[i][j] = __builtin_amdgcn_mfma_i32_16x16x64_i8(a[i], bb[j], acc[i][j], 0, 0, 0);
            }
        }

        // epilogue: C/D layout col=lane&15, row=quad*4+reg
        float sc2[4];
#pragma unroll
        for (int j = 0; j < 4; j++) sc2[j] = sq[col0 + wc * 64 + j * 16 + lcol];

        float cs[4] = {0.f, 0.f, 0.f, 0.f};   // per-lane column partial sums
        const int rslot = 2 * bj + wc;        // row-partial slot
        const int cslot = 2 * bi + wr;        // col-partial slot

#pragma unroll
        for (int i = 0; i < 4; i++) {
            const int rbase = row0 + wr * 64 + i * 16 + quad * 4;
            const float4 s4 = *(const float4*)(sq + rbase);
            const float sr[4] = {s4.x, s4.y, s4.z, s4.w};
            float rs[4] = {0.f, 0.f, 0.f, 0.f};
#pragma unroll
            for (int j = 0; j < 4; j++) {
                const bool extile = diagblk && (wr * 4 + i == wc * 4 + j);
#pragma unroll
                for (int r = 0; r < 4; r++) {
                    // raw v_sqrt_f32 + fused exp2(d*log2e - 22*log2e): 1 trans each
                    float d2 = fmaf(-(float)K2, (float)acc[i][j][r], sr[r] + sc2[j]);
                    float dd = __builtin_amdgcn_sqrtf(fmaxf(d2, 0.f));
                    float e = __builtin_amdgcn_exp2f(fmaf(dd, LOG2E, NSHL2));
                    if (extile && (((quad * 4 + r) >> 3) == (lcol >> 3))) e = 0.f;
                    rs[r] += e;
                    cs[j] += e;
                }
            }
            // row sums: reduce across the 16 lanes of this quad
#pragma unroll
            for (int m = 1; m < 16; m <<= 1) {
#pragma unroll
                for (int r = 0; r < 4; r++) rs[r] += __shfl_xor(rs[r], m);
            }
            if (lcol == 0) {
#pragma unroll
                for (int r = 0; r < 4; r++)
                    P[(size_t)(rbase + r) * PSLOT + rslot] = rs[r];
            }
        }

        if (!diagblk) {
            // column sums: reduce across quads (stride 16, 32), lanes 0..15 hold cols
#pragma unroll
            for (int j = 0; j < 4; j++) {
                cs[j] += __shfl_xor(cs[j], 16);
                cs[j] += __shfl_xor(cs[j], 32);
            }
            if (lane < 16) {
#pragma unroll
                for (int j = 0; j < 4; j++)
                    P[(size_t)(col0 + wc * 64 + j * 16 + lane) * PSLOT + cslot] = cs[j];
            }
        }
    }
}

// per block: 32 rows. Phase 1 reduces P -> Srow[32] (8 lanes/row, coalesced
// 2KB/wave); phase 2: 112 threads each finish one pair from the precomputed
// numerator DD: nll = SHIFT + log(Srow[a] + exp(dd-SHIFT)) - dd.
// ONE atomic to out per block (128 total).
__global__ __launch_bounds__(256) void pairs_kernel(const float* __restrict__ DD,
                                                    const float* __restrict__ P,
                                                    float* __restrict__ out) {
    __shared__ float Srow[FPC * PGRP];
    __shared__ float wsum[4];
    const int tid = threadIdx.x;
    const int base0 = blockIdx.x * (FPC * PGRP);

    {
        const int rl = tid >> 3;     // 0..31 row within block
        const int l8 = tid & 7;
        const float* pr = P + (size_t)(base0 + rl) * PSLOT;
        float s2 = 0.f;
#pragma unroll
        for (int m = 0; m < 8; m++) s2 += pr[l8 + 8 * m];
        s2 += __shfl_xor(s2, 1);
        s2 += __shfl_xor(s2, 2);
        s2 += __shfl_xor(s2, 4);
        if (l8 == 0) Srow[rl] = s2;
    }
    __syncthreads();

    float nll = 0.f;
    if (tid < 28 * PGRP) {
        const int gi = tid / 28;          // group 0..3
        const int pp = tid - gi * 28;     // pair 0..27
        int a = 0, q = pp;
        while (q >= 7 - a) { q -= 7 - a; a++; }
        const float dd = DD[(size_t)(blockIdx.x * PGRP + gi) * 28 + pp];
        nll = SHIFT + __logf(Srow[gi * FPC + a] + __expf(dd - SHIFT)) - dd;
    }
#pragma unroll
    for (int off = 1; off < 64; off <<= 1) nll += __shfl_xor(nll, off);
    if ((tid & 63) == 0) wsum[tid >> 6] = nll;
    __syncthreads();
    if (tid == 0)
        atomicAdd(out, (wsum[0] + wsum[1] + wsum[2] + wsum[3]) * (1.0f / (float)NPAIR));
}

extern "C" void kernel_launch(void* const* d_in, const int* in_sizes, int n_in,
                              void* d_out, int out_size, void* d_ws, size_t ws_size,
                              hipStream_t stream) {
    const float* x = (const float*)d_in[0];
    float* sq = (float*)d_ws;
    float* P  = sq + BATCH;                          // [4096][64] f32, 1 MB
    signed char* xq = (signed char*)(P + (size_t)BATCH * PSLOT);
    float* DD = (float*)(xq + (size_t)BATCH * DIM);  // [512][28] f32
    float* out = (float*)d_out;

    prep_kernel<<<BATCH / 4 + BATCH / (FPC * PGRP), 256, 0, stream>>>(x, sq, xq, DD, out);

    dist_kernel<<<DGRID, 256, 0, stream>>>(xq, sq, P);

    pairs_kernel<<<BATCH / (FPC * PGRP), 256, 0, stream>>>(DD, P, out);
}

// Round 8
// 71.539 us; speedup vs baseline: 1.0355x; 1.0355x over previous
//
#include <hip/hip_runtime.h>
#include <math.h>

#define BATCH 4096
#define DIM 256
#define FPC 8
#define NPAIR 14336   // 512 blocks * C(8,2)
#define SHIFT 22.0f
#define NT 32         // 32 stripes of 128 rows
#define NTILE (NT * (NT + 1) / 2)   // 528 upper-triangular 128x128 tiles
#define S_Q (127.0f / 6.0f)          // int8 quant scale (|x|<6 for N(0,1))
#define K2 (2.0f * (6.0f / 127.0f) * (6.0f / 127.0f))   // d2 -= K2*idot
#define LOG2E 1.442695040888963f
#define NSHL2 (-(SHIFT * LOG2E))     // -22*log2(e): exp(d-22)=exp2(d*log2e+NSHL2)
#define PGRP 4                       // pair-groups per pairs_kernel block
#define PSLOT 64                     // P slots per row (2 per touching tile)

typedef int   i32x4 __attribute__((ext_vector_type(4)));

// async global->LDS, 16B per lane; dest = wave-uniform base + lane*16
__device__ __forceinline__ void g2l16(const void* g, void* l) {
    __builtin_amdgcn_global_load_lds((__attribute__((address_space(1))) void*)(g),
                                     (__attribute__((address_space(3))) void*)(l),
                                     16, 0, 0);
}

// ---------------------------------------------------------------------------
// ws layout (floats): [0,4096) sq ; [4096, 4096+4096*64) P partials ; then
// xq int8 (1 MB). P[r][k]: 64 conflict-free partial exp-sums per row, each
// written exactly once by construction (no zero-init, no atomics):
// row in stripe s gets col-partials in slots 0..2s-1 (from tiles (bi,s),
// 2 wave-rows each), row-partials 2s..63 (from tiles (s,bj), 2 wave-cols).
// 128x128 tiles -> 528 blocks; best-measured config (R6: 72.8us).
// NOTE (R2/R3/R5 lessons): cross-block fusion via completion counters was
// 60-130us SLOWER (agent-RELEASE emits buffer_wbl2 = L2 flush storm; even
// relaxed sc1 paths idle at ~90us). R5: fire-and-forget fp32 atomicAdd into
// S[4096] cost +10us (TCC RMW serialization on shared lines). Plain L2
// store/load + kernel-boundary coherence wins. Do not re-fuse, no atomics.
// R7 lesson: hoisting pair numerators into prep + dist tail-fold = +1.2us
// (neutral/slightly negative) -> reverted. Harness floor per iteration:
// 268MB poison fill (~41us @82% HBM) + ~30 tiny reset dispatches.
// ---------------------------------------------------------------------------

__global__ __launch_bounds__(256) void prep_kernel(const float* __restrict__ x,
                                                   float* __restrict__ sq,
                                                   signed char* __restrict__ xq,
                                                   float* __restrict__ out) {
    int t = blockIdx.x * 256 + threadIdx.x;
    int row = t >> 6;
    int lane = t & 63;
    float4 v = ((const float4*)(x + row * DIM))[lane];
    // int8 symmetric quantization, RNE
    int qx = (int)rintf(v.x * S_Q), qy = (int)rintf(v.y * S_Q);
    int qz = (int)rintf(v.z * S_Q), qw = (int)rintf(v.w * S_Q);
    qx = max(-127, min(127, qx)); qy = max(-127, min(127, qy));
    qz = max(-127, min(127, qz)); qw = max(-127, min(127, qw));
    unsigned pk = (unsigned)(qx & 255) | ((unsigned)(qy & 255) << 8) |
                  ((unsigned)(qz & 255) << 16) | ((unsigned)(qw & 255) << 24);
    ((unsigned*)(xq + (size_t)row * DIM))[lane] = pk;
    float s = v.x * v.x + v.y * v.y + v.z * v.z + v.w * v.w;
#pragma unroll
    for (int off = 32; off > 0; off >>= 1) s += __shfl_xor(s, off);
    if (lane == 0) sq[row] = s;
    if (t == 0) out[0] = 0.f;
}

// 128x128 upper-triangular tile of dist = sqrt(sq_r - 2*s^2*idot + sq_c),
// i8 MFMA K=64, K=256 staged in TWO 128-wide phases -> 32KB LDS.
// 4 waves in 2x2; each wave owns a 64x64 quadrant (4x4 16x16 frags, 64 acc
// VGPRs, 64 MFMAs). Chunk-XOR swizzle (16B chunks, 8/row): global chunk g
// of row r -> slot g^(r&7); reader slot (kk*4+quad)^(lcol&7) -> 2-way bank
// aliasing (free). Row exp-sums -> P[row][2*bj+wc]; off-diag tiles also
// mirrored col exp-sums -> P[col][2*bi+wr].
__global__ __launch_bounds__(256, 2) void dist_kernel(const signed char* __restrict__ xq,
                                                      const float* __restrict__ sq,
                                                      float* __restrict__ P) {
    __shared__ signed char As[128][128];   // 16KB
    __shared__ signed char Bs[128][128];   // 16KB

    // triangular decode: tile (bi, bj) with bi <= bj
    int t = blockIdx.x, bi = 0;
    while (t >= NT - bi) { t -= NT - bi; bi++; }
    const int bj = bi + t;
    const int row0 = bi * 128;
    const int col0 = bj * 128;
    const bool diagblk = (bi == bj);

    const int tid  = threadIdx.x;
    const int w    = tid >> 6;      // wave 0..3
    const int lane = tid & 63;
    const int wr   = w >> 1;        // wave row 0..1 (64-row half)
    const int wc   = w & 1;         // wave col 0..1
    const int quad = lane >> 4;     // 0..3
    const int lcol = lane & 15;     // 0..15

    // staging: one g2l16 = 8 rows x 128B; lane -> (row lane>>3, chunk lane&7)
    const int srow = lane >> 3;     // 0..7
    const int schk = lane & 7;      // linear LDS chunk (16B units)
    const int gc = (schk ^ (srow & 7)) * 16;   // swizzled global chunk (bytes)
    const int ldsoff = lane * 16;   // linear LDS dest (bytes)

    i32x4 acc[4][4];
#pragma unroll
    for (int i = 0; i < 4; i++)
#pragma unroll
        for (int j = 0; j < 4; j++) {
            i32x4 z = {0, 0, 0, 0};
            acc[i][j] = z;
        }

#pragma unroll
    for (int ph = 0; ph < 2; ph++) {
        const int k0 = ph * 128;
        if (ph) __syncthreads();    // prior phase's reads done before overwrite
#pragma unroll
        for (int c = 0; c < 4; c++) {
            const int rb = w * 32 + c * 8;   // wave w stages rows [w*32, w*32+32)
            const int r  = rb + srow;
            g2l16(xq + (size_t)(row0 + r) * DIM + k0 + gc, (signed char*)&As[rb][0] + ldsoff);
            g2l16(xq + (size_t)(col0 + r) * DIM + k0 + gc, (signed char*)&Bs[rb][0] + ldsoff);
        }
        __syncthreads();            // drain: 32KB staged

#pragma unroll
        for (int kk = 0; kk < 2; kk++) {
            const int slot = ((kk * 4 + quad) ^ (lcol & 7)) * 16;
            i32x4 a[4], bb[4];
#pragma unroll
            for (int i = 0; i < 4; i++)
                a[i] = *(const i32x4*)&As[wr * 64 + i * 16 + lcol][slot];
#pragma unroll
            for (int j = 0; j < 4; j++)
                bb[j] = *(const i32x4*)&Bs[wc * 64 + j * 16 + lcol][slot];
#pragma unroll
            for (int i = 0; i < 4; i++)
#pragma unroll
                for (int j = 0; j < 4; j++)
                    acc[i][j] = __builtin_amdgcn_mfma_i32_16x16x64_i8(a[i], bb[j], acc[i][j], 0, 0, 0);
        }
    }

    // epilogue: C/D layout col=lane&15, row=quad*4+reg
    float sc2[4];
#pragma unroll
    for (int j = 0; j < 4; j++) sc2[j] = sq[col0 + wc * 64 + j * 16 + lcol];

    float cs[4] = {0.f, 0.f, 0.f, 0.f};   // per-lane column partial sums
    const int rslot = 2 * bj + wc;        // row-partial slot
    const int cslot = 2 * bi + wr;        // col-partial slot

#pragma unroll
    for (int i = 0; i < 4; i++) {
        const int rbase = row0 + wr * 64 + i * 16 + quad * 4;
        const float4 s4 = *(const float4*)(sq + rbase);
        const float sr[4] = {s4.x, s4.y, s4.z, s4.w};
        float rs[4] = {0.f, 0.f, 0.f, 0.f};
#pragma unroll
        for (int j = 0; j < 4; j++) {
            const bool extile = diagblk && (wr * 4 + i == wc * 4 + j);
#pragma unroll
            for (int r = 0; r < 4; r++) {
                // raw v_sqrt_f32 + fused exp2(d*log2e - 22*log2e): 1 trans each
                float d2 = fmaf(-(float)K2, (float)acc[i][j][r], sr[r] + sc2[j]);
                float dd = __builtin_amdgcn_sqrtf(fmaxf(d2, 0.f));
                float e = __builtin_amdgcn_exp2f(fmaf(dd, LOG2E, NSHL2));
                if (extile && (((quad * 4 + r) >> 3) == (lcol >> 3))) e = 0.f;
                rs[r] += e;
                cs[j] += e;
            }
        }
        // row sums: reduce across the 16 lanes of this quad
#pragma unroll
        for (int m = 1; m < 16; m <<= 1) {
#pragma unroll
            for (int r = 0; r < 4; r++) rs[r] += __shfl_xor(rs[r], m);
        }
        if (lcol == 0) {
#pragma unroll
            for (int r = 0; r < 4; r++)
                P[(size_t)(rbase + r) * PSLOT + rslot] = rs[r];
        }
    }

    if (!diagblk) {
        // column sums: reduce across quads (stride 16, 32), lanes 0..15 hold cols
#pragma unroll
        for (int j = 0; j < 4; j++) {
            cs[j] += __shfl_xor(cs[j], 16);
            cs[j] += __shfl_xor(cs[j], 32);
        }
        if (lane < 16) {
#pragma unroll
            for (int j = 0; j < 4; j++)
                P[(size_t)(col0 + wc * 64 + j * 16 + lane) * PSLOT + cslot] = cs[j];
        }
    }
}

// per block: 4 FPC-groups (32 rows). Phase 1 reduces P -> Srow[32] in one
// pass (8 lanes per row, 64 slots); phase 2 loops the 4 groups' 28
// within-block fp32 distances -> nll; ONE atomic per block (128 total).
__global__ __launch_bounds__(256) void pairs_kernel(const float* __restrict__ x,
                                                    const float* __restrict__ P,
                                                    float* __restrict__ out) {
    __shared__ float Srow[FPC * PGRP];
    __shared__ float wsum[4];
    const int tid = threadIdx.x;
    const int base0 = blockIdx.x * (FPC * PGRP);

    {
        const int rl = tid >> 3;     // 0..31 row within block
        const int l8 = tid & 7;
        const float* pr = P + (size_t)(base0 + rl) * PSLOT;
        float s2 = 0.f;
#pragma unroll
        for (int m = 0; m < 8; m++) s2 += pr[l8 + 8 * m];
        s2 += __shfl_xor(s2, 1);
        s2 += __shfl_xor(s2, 2);
        s2 += __shfl_xor(s2, 4);
        if (l8 == 0) Srow[rl] = s2;
    }
    __syncthreads();

    const int p = tid >> 3;     // pair id 0..31 (28 used)
    const int g = tid & 7;      // lane within pair group
    int a = 0, b = 0;
    if (p < 28) {
        int q = p;
        while (q >= 7 - a) { q -= 7 - a; a++; }
        b = a + 1 + q;                          // anchor=a, positive=b
    }

    float nll = 0.f;
#pragma unroll
    for (int it = 0; it < PGRP; it++) {
        if (p < 28) {
            const int base = base0 + it * FPC;
            const float4* xa  = (const float4*)(x + (size_t)(base + a) * DIM);
            const float4* xbp = (const float4*)(x + (size_t)(base + b) * DIM);
            float d2 = 0.f;
#pragma unroll
            for (int r = 0; r < 8; r++) {
                float4 va = xa[r * 8 + g], vb = xbp[r * 8 + g];
                float dx = va.x - vb.x, dy = va.y - vb.y;
                float dz = va.z - vb.z, dw = va.w - vb.w;
                d2 = fmaf(dx, dx, d2); d2 = fmaf(dy, dy, d2);
                d2 = fmaf(dz, dz, d2); d2 = fmaf(dw, dw, d2);
            }
            d2 += __shfl_xor(d2, 1);
            d2 += __shfl_xor(d2, 2);
            d2 += __shfl_xor(d2, 4);
            if (g == 0) {
                float dd = sqrtf(fmaxf(d2, 0.f));
                nll += SHIFT + __logf(Srow[it * FPC + a] + __expf(dd - SHIFT)) - dd;
            }
        }
    }
#pragma unroll
    for (int off = 1; off < 64; off <<= 1) nll += __shfl_xor(nll, off);
    if ((tid & 63) == 0) wsum[tid >> 6] = nll;
    __syncthreads();
    if (tid == 0)
        atomicAdd(out, (wsum[0] + wsum[1] + wsum[2] + wsum[3]) * (1.0f / (float)NPAIR));
}

extern "C" void kernel_launch(void* const* d_in, const int* in_sizes, int n_in,
                              void* d_out, int out_size, void* d_ws, size_t ws_size,
                              hipStream_t stream) {
    const float* x = (const float*)d_in[0];
    float* sq = (float*)d_ws;
    float* P  = sq + BATCH;                          // [4096][64] f32, 1 MB
    signed char* xq = (signed char*)(P + (size_t)BATCH * PSLOT);
    float* out = (float*)d_out;

    prep_kernel<<<BATCH * 64 / 256, 256, 0, stream>>>(x, sq, xq, out);

    dist_kernel<<<NTILE, 256, 0, stream>>>(xq, sq, P);

    pairs_kernel<<<BATCH / (FPC * PGRP), 256, 0, stream>>>(x, P, out);
}